// Round 2
// baseline (709.054 us; speedup 1.0000x reference)
//
#include <hip/hip_runtime.h>
#include <hip/hip_bf16.h>

#define SCALE 0.17677669529663687f  // 1/sqrt(32)

// ---------------------------------------------------------------------------
// Kernel 1: bias[h][i][j] = sum_z pair[i][j][z] * bias_proj[z][h]
// grid 256 blocks x 256 threads; one thread per (i,j), all 8 heads.
// ---------------------------------------------------------------------------
__global__ __launch_bounds__(256) void bias_kernel(
    const float* __restrict__ pair, const float* __restrict__ bias_w,
    float* __restrict__ bias) {
  __shared__ float Bp[1024];  // [z][h] 128x8
  const int t = threadIdx.x;
  for (int i = t; i < 1024; i += 256) Bp[i] = bias_w[i];
  __syncthreads();

  const int ij = blockIdx.x * 256 + t;   // 0..65535
  const int i = ij >> 8, j = ij & 255;
  const float* pr = pair + (size_t)ij * 128;

  float acc[8] = {};
  for (int z4 = 0; z4 < 128; z4 += 4) {
    float4 pv = *(const float4*)&pr[z4];
    const float pe[4] = {pv.x, pv.y, pv.z, pv.w};
#pragma unroll
    for (int u = 0; u < 4; ++u) {
#pragma unroll
      for (int h = 0; h < 8; ++h)
        acc[h] = fmaf(pe[u], Bp[(z4 + u) * 8 + h], acc[h]);
    }
  }
#pragma unroll
  for (int h = 0; h < 8; ++h)
    bias[((size_t)h * 256 + i) * 256 + j] = acc[h];
}

// ---------------------------------------------------------------------------
// Kernel 2: generic f32 tiled GEMM  C[M,N] = A[M,K] @ B[K,N], optional sigmoid
// 64x64 tile, K-step 16, 256 threads, 4x4 microtile per thread.
// M%64==0, N%64==0, K%16==0 assumed (holds for all our shapes).
// ---------------------------------------------------------------------------
template <bool SIGMOID>
__global__ __launch_bounds__(256) void gemm_f32(
    const float* __restrict__ A, const float* __restrict__ B,
    float* __restrict__ C, int M, int N, int K) {
  __shared__ float As[16][68];  // [k][m], padded
  __shared__ float Bs[16][64];  // [k][n]

  const int tid = threadIdx.x;
  const int m0 = blockIdx.y * 64;
  const int n0 = blockIdx.x * 64;
  const int tx = tid & 15, ty = tid >> 4;

  // global-load assignments
  const int ar = tid >> 2;          // 0..63 row (m) within tile
  const int ac = (tid & 3) << 2;    // 0,4,8,12 (k) within tile
  const int br = tid >> 4;          // 0..15 (k)
  const int bc = (tid & 15) << 2;   // col (n) within tile

  float acc[4][4] = {};

  for (int k0 = 0; k0 < K; k0 += 16) {
    float4 av = *(const float4*)&A[(size_t)(m0 + ar) * K + k0 + ac];
    float4 bv = *(const float4*)&B[(size_t)(k0 + br) * N + n0 + bc];
    __syncthreads();  // previous compute done before overwriting LDS
    As[ac + 0][ar] = av.x;
    As[ac + 1][ar] = av.y;
    As[ac + 2][ar] = av.z;
    As[ac + 3][ar] = av.w;
    *(float4*)&Bs[br][bc] = bv;
    __syncthreads();
#pragma unroll
    for (int k = 0; k < 16; ++k) {
      float a[4], b[4];
#pragma unroll
      for (int i = 0; i < 4; ++i) a[i] = As[k][ty * 4 + i];
#pragma unroll
      for (int j = 0; j < 4; ++j) b[j] = Bs[k][tx * 4 + j];
#pragma unroll
      for (int i = 0; i < 4; ++i)
#pragma unroll
        for (int j = 0; j < 4; ++j)
          acc[i][j] = fmaf(a[i], b[j], acc[i][j]);
    }
  }

#pragma unroll
  for (int i = 0; i < 4; ++i) {
#pragma unroll
    for (int j = 0; j < 4; ++j) {
      float v = acc[i][j];
      if (SIGMOID) v = 1.0f / (1.0f + __expf(-v));
      C[(size_t)(m0 + ty * 4 + i) * N + n0 + tx * 4 + j] = v;
    }
  }
}

// ---------------------------------------------------------------------------
// Kernel 3: attention per (s,h). Block = 256 threads = 256 query rows.
//   attend[s,q,h,:] = ( softmax_k(q.K^T*scale) . V + bias_h . V ) * gate
// gate buffer is read then overwritten in-place with the result (same elems).
// ---------------------------------------------------------------------------
__global__ __launch_bounds__(256) void attn_kernel(
    const float* __restrict__ qkv, const float* __restrict__ bias,
    float* __restrict__ gate_attend /* in: gate, out: attend*gate */) {
  const int s = blockIdx.x >> 3;
  const int h = blockIdx.x & 7;
  const int t = threadIdx.x;  // query row (and K/V row for loading)

  __shared__ float Ks[256][32];
  __shared__ float Vs[256][32];

  const size_t rowbase = ((size_t)(s * 256 + t)) * 768;
  const float* kro = qkv + rowbase + 256 + h * 32;
  const float* vro = qkv + rowbase + 512 + h * 32;
#pragma unroll
  for (int c = 0; c < 32; c += 4) {
    *(float4*)&Ks[t][c] = *(const float4*)&kro[c];
    *(float4*)&Vs[t][c] = *(const float4*)&vro[c];
  }

  // q into registers
  float qv[32];
  const float* qro = qkv + rowbase + h * 32;
#pragma unroll
  for (int c = 0; c < 32; c += 4) {
    float4 v = *(const float4*)&qro[c];
    qv[c] = v.x; qv[c + 1] = v.y; qv[c + 2] = v.z; qv[c + 3] = v.w;
  }
  __syncthreads();

  const float* brow = bias + ((size_t)h * 256 + t) * 256;

  float l = 0.0f;
  float o1[32] = {};  // softmax(P).V numerator
  float o2[32] = {};  // bias.V
  for (int k = 0; k < 256; ++k) {
    float sdot = 0.0f;
#pragma unroll
    for (int c = 0; c < 32; ++c) sdot = fmaf(qv[c], Ks[k][c], sdot);
    float e = __expf(sdot * SCALE);
    l += e;
    float b = brow[k];
#pragma unroll
    for (int c = 0; c < 32; ++c) {
      o1[c] = fmaf(e, Vs[k][c], o1[c]);
      o2[c] = fmaf(b, Vs[k][c], o2[c]);
    }
  }

  const float rl = 1.0f / l;
  float* grow = gate_attend + ((size_t)(s * 256 + t)) * 256 + h * 32;
#pragma unroll
  for (int c = 0; c < 32; c += 4) {
    float4 g = *(const float4*)&grow[c];
    float4 o;
    o.x = (o1[c + 0] * rl + o2[c + 0]) * g.x;
    o.y = (o1[c + 1] * rl + o2[c + 1]) * g.y;
    o.z = (o1[c + 2] * rl + o2[c + 2]) * g.z;
    o.w = (o1[c + 3] * rl + o2[c + 3]) * g.w;
    *(float4*)&grow[c] = o;
  }
}

// ---------------------------------------------------------------------------
extern "C" void kernel_launch(void* const* d_in, const int* in_sizes, int n_in,
                              void* d_out, int out_size, void* d_ws,
                              size_t ws_size, hipStream_t stream) {
  const float* msa    = (const float*)d_in[0];  // [1,128,256,256]
  const float* pair   = (const float*)d_in[1];  // [1,256,256,128]
  const float* gate_w = (const float*)d_in[2];  // [256,256]
  const float* qkv_w  = (const float*)d_in[3];  // [256,768]
  const float* out_w  = (const float*)d_in[4];  // [256,256]
  const float* bias_w = (const float*)d_in[5];  // [128,8]
  float* out = (float*)d_out;                   // [1,128,256,256]

  char* ws = (char*)d_ws;
  float* qkv    = (float*)ws;                        // 32768*768*4 = 100663296
  float* gatebf = (float*)(ws + 100663296);          // 32768*256*4 = 33554432 (gate -> attend in-place)
  float* bias   = (float*)(ws + 100663296 + 33554432);  // 8*256*256*4 = 2097152

  const int M = 32768;  // S*R

  // 1) pair bias
  bias_kernel<<<256, 256, 0, stream>>>(pair, bias_w, bias);

  // 2) gate = sigmoid(msa @ gate_w)   [M,256]
  gemm_f32<true><<<dim3(4, M / 64), 256, 0, stream>>>(msa, gate_w, gatebf, M, 256, 256);

  // 3) qkv = msa @ qkv_w              [M,768]
  gemm_f32<false><<<dim3(12, M / 64), 256, 0, stream>>>(msa, qkv_w, qkv, M, 768, 256);

  // 4) attention (writes attend*gate in-place into gatebf)
  attn_kernel<<<1024, 256, 0, stream>>>(qkv, bias, gatebf);

  // 5) out = attend @ out_w           [M,256]
  gemm_f32<false><<<dim3(4, M / 64), 256, 0, stream>>>(gatebf, out_w, out, M, 256, 256);
}

// Round 5
// 238.186 us; speedup vs baseline: 2.9769x; 2.9769x over previous
//
#include <hip/hip_runtime.h>
#include <hip/hip_bf16.h>
#include <stdint.h>

#define SCALE 0.17677669529663687f  // 1/sqrt(32)

typedef short bf8 __attribute__((ext_vector_type(8)));    // 8 bf16 (4 VGPR)
typedef float f32x4 __attribute__((ext_vector_type(4)));  // MFMA acc

__device__ __forceinline__ short f2bf(float f) {
  unsigned u = __builtin_bit_cast(unsigned, f);
  u = (u + 0x7FFFu + ((u >> 16) & 1u)) >> 16;  // RNE
  return (short)u;
}
__device__ __forceinline__ float bf2f(short s) {
  return __builtin_bit_cast(float, ((unsigned)(unsigned short)s) << 16);
}
__device__ __forceinline__ void gl_lds16(const void* g, void* l) {
  __builtin_amdgcn_global_load_lds(
      (const __attribute__((address_space(1))) unsigned int*)g,
      (__attribute__((address_space(3))) unsigned int*)l, 16, 0, 0);
}

// ---------------------------------------------------------------------------
// msa f32 -> bf16, vectorized (float4 in, short4 out)
// ---------------------------------------------------------------------------
__global__ __launch_bounds__(256) void convert_msa(
    const float* __restrict__ in, short* __restrict__ out, int n4) {
  int i = blockIdx.x * 256 + threadIdx.x;
  const int stride = gridDim.x * 256;
  for (; i < n4; i += stride) {
    float4 v = ((const float4*)in)[i];
    short4 o;
    o.x = f2bf(v.x); o.y = f2bf(v.y); o.z = f2bf(v.z); o.w = f2bf(v.w);
    ((short4*)out)[i] = o;
  }
}

// ---------------------------------------------------------------------------
// weights: wcat_t[n][k] = (n<256? gate_w[k][n] : qkv_w[k][n-256]) as bf16
//          owt[n][k]    = out_w[k][n] as bf16
// ---------------------------------------------------------------------------
__global__ __launch_bounds__(256) void prep_w(
    const float* __restrict__ gw, const float* __restrict__ qw,
    const float* __restrict__ ow, short* __restrict__ wcat,
    short* __restrict__ owt) {
  int i = blockIdx.x * 256 + threadIdx.x;  // 0..327679
  if (i < 262144) {
    int n = i >> 8, k = i & 255;
    wcat[i] = f2bf(n < 256 ? gw[k * 256 + n] : qw[k * 768 + (n - 256)]);
  } else if (i < 327680) {
    int j = i - 262144;
    int n = j >> 8, k = j & 255;
    owt[j] = f2bf(ow[k * 256 + n]);
  }
}

// ---------------------------------------------------------------------------
// bias_bf[h][i][j] = sum_z pair[i][j][z] * bias_w[z][h]   (bf16 out)
// ---------------------------------------------------------------------------
__global__ __launch_bounds__(256) void bias_kernel(
    const float* __restrict__ pair, const float* __restrict__ bias_w,
    short* __restrict__ bias) {
  __shared__ float Bp[1024];  // [z][h] 128x8
  const int t = threadIdx.x;
  for (int i = t; i < 1024; i += 256) Bp[i] = bias_w[i];
  __syncthreads();

  const int ij = blockIdx.x * 256 + t;
  const float* pr = pair + (size_t)ij * 128;

  float acc[8] = {};
  for (int z4 = 0; z4 < 128; z4 += 4) {
    float4 pv = *(const float4*)&pr[z4];
    const float pe[4] = {pv.x, pv.y, pv.z, pv.w};
#pragma unroll
    for (int u = 0; u < 4; ++u)
#pragma unroll
      for (int h = 0; h < 8; ++h)
        acc[h] = fmaf(pe[u], Bp[(z4 + u) * 8 + h], acc[h]);
  }
#pragma unroll
  for (int h = 0; h < 8; ++h)
    bias[(size_t)h * 65536 + ij] = f2bf(acc[h]);
}

// ---------------------------------------------------------------------------
// bf16 MFMA GEMM, 128x128 tile, BK=32, 4 waves (each 64x64), global_load_lds.
// A [M][K] bf16, Bt [N][K] bf16 (B transposed).
// MODE 0: cols<256 -> sigmoid -> gate (ld 256); cols>=256 -> qkv (ld 768). bf16.
// MODE 1: f32 C [M][N].
// ---------------------------------------------------------------------------
template <int MODE>
__global__ __launch_bounds__(256) void gemm_bf16(
    const short* __restrict__ A, const short* __restrict__ Bt,
    void* __restrict__ C0, void* __restrict__ C1, int M, int N, int K) {
  __shared__ short As[128 * 32];
  __shared__ short Bs[128 * 32];
  const int tid = threadIdx.x;
  const int lane = tid & 63, w = tid >> 6;
  const int l15 = lane & 15, l4 = lane >> 4;
  const int m0 = blockIdx.y * 128, n0 = blockIdx.x * 128;
  const int wm = (w >> 1) * 64, wn = (w & 1) * 64;

  f32x4 acc[4][4];
#pragma unroll
  for (int i = 0; i < 4; ++i)
#pragma unroll
    for (int j = 0; j < 4; ++j) acc[i][j] = (f32x4)(0.0f);

  // staging: wave w fills rows [w*32, w*32+32) of As and Bs.
  // one gl_lds16 call = 64 lanes * 16B = 1KB = 16 rows (4 lanes/row)
  const int srow = w * 32 + (lane >> 2);
  const int scol = (lane & 3) * 8;  // elem offset within 32-elem row chunk

  for (int k0 = 0; k0 < K; k0 += 32) {
    __syncthreads();  // previous compute done before overwriting LDS
    gl_lds16(A + (size_t)(m0 + srow) * K + k0 + scol, &As[(w * 32) * 32]);
    gl_lds16(A + (size_t)(m0 + srow + 16) * K + k0 + scol, &As[(w * 32 + 16) * 32]);
    gl_lds16(Bt + (size_t)(n0 + srow) * K + k0 + scol, &Bs[(w * 32) * 32]);
    gl_lds16(Bt + (size_t)(n0 + srow + 16) * K + k0 + scol, &Bs[(w * 32 + 16) * 32]);
    __syncthreads();  // implicit vmcnt(0) drain makes LDS data visible
#pragma unroll
    for (int nf = 0; nf < 4; ++nf) {
      bf8 bfr = *(const bf8*)(&Bs[(wn + nf * 16 + l15) * 32 + l4 * 8]);
#pragma unroll
      for (int mf = 0; mf < 4; ++mf) {
        bf8 afr = *(const bf8*)(&As[(wm + mf * 16 + l15) * 32 + l4 * 8]);
        acc[mf][nf] =
            __builtin_amdgcn_mfma_f32_16x16x32_bf16(afr, bfr, acc[mf][nf], 0, 0, 0);
      }
    }
  }

#pragma unroll
  for (int mf = 0; mf < 4; ++mf)
#pragma unroll
    for (int nf = 0; nf < 4; ++nf)
#pragma unroll
      for (int r = 0; r < 4; ++r) {
        const int m = m0 + wm + mf * 16 + l4 * 4 + r;
        const int n = n0 + wn + nf * 16 + l15;
        float v = acc[mf][nf][r];
        if (MODE == 0) {
          if (n < 256)
            ((short*)C0)[(size_t)m * 256 + n] = f2bf(1.0f / (1.0f + __expf(-v)));
          else
            ((short*)C1)[(size_t)m * 768 + (n - 256)] = f2bf(v);
        } else {
          ((float*)C0)[(size_t)m * N + n] = v;
        }
      }
}

// ---------------------------------------------------------------------------
// MFMA attention per (s,h). 256 threads = 4 waves; wave w owns q-rows
// [w*64, w*64+64). Flash over 4 k-chunks of 64. No-max softmax (sum of exp).
//   attendg = ( exp(S)·V / l + B·V ) * gate,   all contractions via MFMA.
// ---------------------------------------------------------------------------
__global__ __launch_bounds__(256) void attn_mfma(
    const short* __restrict__ qkv,    // [32768][768] bf16
    const short* __restrict__ bias,   // [8][256][256] bf16
    const short* __restrict__ gate,   // [32768][256] bf16
    short* __restrict__ attendg) {    // [32768][256] bf16 out
  const int s = blockIdx.x >> 3;
  const int h = blockIdx.x & 7;
  const int tid = threadIdx.x;
  const int lane = tid & 63, w = tid >> 6;
  const int l15 = lane & 15, l4 = lane >> 4;

  __shared__ short Vt[32][264];        // V^T, padded (row stride 528B: 2-way free)
  __shared__ short Plds[4][64][72];    // per-wave exp(S) chunk, padded

  // ---- stage V^T: thread t loads V row t (32 bf16), writes column t
  {
    const short* vrow = qkv + (size_t)(s * 256 + tid) * 768 + 512 + h * 32;
    short tmp[32];
    *(int4*)(tmp +  0) = *(const int4*)(vrow +  0);
    *(int4*)(tmp +  8) = *(const int4*)(vrow +  8);
    *(int4*)(tmp + 16) = *(const int4*)(vrow + 16);
    *(int4*)(tmp + 24) = *(const int4*)(vrow + 24);
#pragma unroll
    for (int c = 0; c < 32; ++c) Vt[c][tid] = tmp[c];
  }

  // ---- Q fragments in registers (reused across all k-chunks)
  bf8 qf[4];
  const int q0 = w * 64;
#pragma unroll
  for (int mf = 0; mf < 4; ++mf)
    qf[mf] = *(const bf8*)(qkv + (size_t)(s * 256 + q0 + mf * 16 + l15) * 768 +
                           h * 32 + l4 * 8);

  __syncthreads();  // Vt ready

  f32x4 o1[4][2], o2[4][2];
  float lsum[16];
#pragma unroll
  for (int mf = 0; mf < 4; ++mf)
#pragma unroll
    for (int nf = 0; nf < 2; ++nf) {
      o1[mf][nf] = (f32x4)(0.0f);
      o2[mf][nf] = (f32x4)(0.0f);
    }
#pragma unroll
  for (int i = 0; i < 16; ++i) lsum[i] = 0.0f;

  for (int kb = 0; kb < 4; ++kb) {
    // ---- S chunk = Q · K^T (64q x 64k per wave), K frags direct from global
    f32x4 sa[4][4];
#pragma unroll
    for (int nf = 0; nf < 4; ++nf) {
      bf8 kf = *(const bf8*)(qkv +
                             (size_t)(s * 256 + kb * 64 + nf * 16 + l15) * 768 +
                             256 + h * 32 + l4 * 8);
#pragma unroll
      for (int mf = 0; mf < 4; ++mf)
        sa[mf][nf] =
            __builtin_amdgcn_mfma_f32_16x16x32_bf16(qf[mf], kf, (f32x4)(0.0f), 0, 0, 0);
    }

    __syncthreads();  // previous chunk's PV reads of Plds complete
    // ---- exp + row-sum partials + spill P (bf16) to LDS for re-fragmenting
#pragma unroll
    for (int mf = 0; mf < 4; ++mf)
#pragma unroll
      for (int nf = 0; nf < 4; ++nf)
#pragma unroll
        for (int r = 0; r < 4; ++r) {
          float e = __expf(sa[mf][nf][r] * SCALE);
          lsum[mf * 4 + r] += e;
          Plds[w][mf * 16 + l4 * 4 + r][nf * 16 + l15] = f2bf(e);
        }
    __syncthreads();  // P visible

    // ---- PV (o1) and B·V (o2); bias frags direct from global (L3-resident)
#pragma unroll
    for (int ks = 0; ks < 2; ++ks) {
      bf8 vf[2];
#pragma unroll
      for (int nf = 0; nf < 2; ++nf)
        vf[nf] = *(const bf8*)(&Vt[nf * 16 + l15][kb * 64 + ks * 32 + l4 * 8]);
#pragma unroll
      for (int mf = 0; mf < 4; ++mf) {
        bf8 pf = *(const bf8*)(&Plds[w][mf * 16 + l15][ks * 32 + l4 * 8]);
        bf8 bfr = *(const bf8*)(bias + ((size_t)h * 256 + q0 + mf * 16 + l15) * 256 +
                                kb * 64 + ks * 32 + l4 * 8);
#pragma unroll
        for (int nf = 0; nf < 2; ++nf) {
          o1[mf][nf] = __builtin_amdgcn_mfma_f32_16x16x32_bf16(pf, vf[nf], o1[mf][nf], 0, 0, 0);
          o2[mf][nf] = __builtin_amdgcn_mfma_f32_16x16x32_bf16(bfr, vf[nf], o2[mf][nf], 0, 0, 0);
        }
      }
    }
  }

  // ---- row sums: reduce over the 16 lanes sharing each q-row set
#pragma unroll
  for (int i = 0; i < 16; ++i) {
    float v = lsum[i];
    v += __shfl_xor(v, 1);
    v += __shfl_xor(v, 2);
    v += __shfl_xor(v, 4);
    v += __shfl_xor(v, 8);
    lsum[i] = 1.0f / v;
  }

  // ---- epilogue: normalize, add bias term, gate, store bf16
#pragma unroll
  for (int mf = 0; mf < 4; ++mf)
#pragma unroll
    for (int nf = 0; nf < 2; ++nf)
#pragma unroll
      for (int r = 0; r < 4; ++r) {
        const int q = q0 + mf * 16 + l4 * 4 + r;
        const int c = nf * 16 + l15;
        const size_t off = (size_t)(s * 256 + q) * 256 + h * 32 + c;
        float val = o1[mf][nf][r] * lsum[mf * 4 + r] + o2[mf][nf][r];
        attendg[off] = f2bf(val * bf2f(gate[off]));
      }
}

// ---------------------------------------------------------------------------
extern "C" void kernel_launch(void* const* d_in, const int* in_sizes, int n_in,
                              void* d_out, int out_size, void* d_ws,
                              size_t ws_size, hipStream_t stream) {
  const float* msa    = (const float*)d_in[0];  // [32768][256]
  const float* pair   = (const float*)d_in[1];  // [65536][128]
  const float* gate_w = (const float*)d_in[2];  // [256][256]
  const float* qkv_w  = (const float*)d_in[3];  // [256][768]
  const float* out_w  = (const float*)d_in[4];  // [256][256]
  const float* bias_w = (const float*)d_in[5];  // [128][8]
  float* out = (float*)d_out;                   // [32768][256] f32

  char* ws = (char*)d_ws;
  short* qkv_bf  = (short*)(ws);                 // 50,331,648 B
  short* msa_bf  = (short*)(ws + 50331648);      // 16,777,216 B
  short* gate_bf = (short*)(ws + 67108864);      // 16,777,216 B
  short* attendg = (short*)(ws + 83886080);      // 16,777,216 B
  short* bias_bf = (short*)(ws + 100663296);     //  1,048,576 B
  short* wcat_t  = (short*)(ws + 101711872);     //    524,288 B
  short* owt     = (short*)(ws + 102236160);     //    131,072 B

  const int M = 32768;

  convert_msa<<<2048, 256, 0, stream>>>(msa, msa_bf, M * 256 / 4);
  prep_w<<<1280, 256, 0, stream>>>(gate_w, qkv_w, out_w, wcat_t, owt);
  bias_kernel<<<256, 256, 0, stream>>>(pair, bias_w, bias_bf);

  // gate|qkv fused GEMM: [M,256] @ [256,1024]
  gemm_bf16<0><<<dim3(8, M / 128), 256, 0, stream>>>(
      msa_bf, wcat_t, gate_bf, qkv_bf, M, 1024, 256);

  attn_mfma<<<1024, 256, 0, stream>>>(qkv_bf, bias_bf, gate_bf, attendg);

  // out GEMM: [M,256] @ [256,256] -> f32
  gemm_bf16<1><<<dim3(2, M / 128), 256, 0, stream>>>(
      attendg, owt, out, nullptr, M, 256, 256);
}

// Round 6
// 236.866 us; speedup vs baseline: 2.9935x; 1.0056x over previous
//
#include <hip/hip_runtime.h>
#include <hip/hip_bf16.h>
#include <stdint.h>

#define QSCALE 0.2550348552724541f  // (1/sqrt(32)) * log2(e), folded into q

typedef short bf8 __attribute__((ext_vector_type(8)));    // 8 bf16 (4 VGPR)
typedef float f32x4 __attribute__((ext_vector_type(4)));  // MFMA acc

__device__ __forceinline__ short f2bf(float f) {
  unsigned u = __builtin_bit_cast(unsigned, f);
  u = (u + 0x7FFFu + ((u >> 16) & 1u)) >> 16;  // RNE
  return (short)u;
}
__device__ __forceinline__ float bf2f(short s) {
  return __builtin_bit_cast(float, ((unsigned)(unsigned short)s) << 16);
}
__device__ __forceinline__ void gl_lds16(const void* g, void* l) {
  __builtin_amdgcn_global_load_lds(
      (const __attribute__((address_space(1))) unsigned int*)g,
      (__attribute__((address_space(3))) unsigned int*)l, 16, 0, 0);
}

// ---------------------------------------------------------------------------
// msa f32 -> bf16, vectorized (float4 in, short4 out)
// ---------------------------------------------------------------------------
__global__ __launch_bounds__(256) void convert_msa(
    const float* __restrict__ in, short* __restrict__ out, int n4) {
  int i = blockIdx.x * 256 + threadIdx.x;
  const int stride = gridDim.x * 256;
  for (; i < n4; i += stride) {
    float4 v = ((const float4*)in)[i];
    short4 o;
    o.x = f2bf(v.x); o.y = f2bf(v.y); o.z = f2bf(v.z); o.w = f2bf(v.w);
    ((short4*)out)[i] = o;
  }
}

// ---------------------------------------------------------------------------
// weights: wcat_t[n][k] = (n<256? gate_w[k][n] : qkv_w[k][n-256]) as bf16
//          owt[n][k]    = out_w[k][n] as bf16
// ---------------------------------------------------------------------------
__global__ __launch_bounds__(256) void prep_w(
    const float* __restrict__ gw, const float* __restrict__ qw,
    const float* __restrict__ ow, short* __restrict__ wcat,
    short* __restrict__ owt) {
  int i = blockIdx.x * 256 + threadIdx.x;  // 0..327679
  if (i < 262144) {
    int n = i >> 8, k = i & 255;
    wcat[i] = f2bf(n < 256 ? gw[k * 256 + n] : qw[k * 768 + (n - 256)]);
  } else if (i < 327680) {
    int j = i - 262144;
    int n = j >> 8, k = j & 255;
    owt[j] = f2bf(ow[k * 256 + n]);
  }
}

// ---------------------------------------------------------------------------
// bias_bf[h][i][j] = sum_z pair[i][j][z] * bias_w[z][h]   (bf16 out)
// ---------------------------------------------------------------------------
__global__ __launch_bounds__(256) void bias_kernel(
    const float* __restrict__ pair, const float* __restrict__ bias_w,
    short* __restrict__ bias) {
  __shared__ float Bp[1024];  // [z][h] 128x8
  const int t = threadIdx.x;
  for (int i = t; i < 1024; i += 256) Bp[i] = bias_w[i];
  __syncthreads();

  const int ij = blockIdx.x * 256 + t;
  const float* pr = pair + (size_t)ij * 128;

  float acc[8] = {};
  for (int z4 = 0; z4 < 128; z4 += 4) {
    float4 pv = *(const float4*)&pr[z4];
    const float pe[4] = {pv.x, pv.y, pv.z, pv.w};
#pragma unroll
    for (int u = 0; u < 4; ++u)
#pragma unroll
      for (int h = 0; h < 8; ++h)
        acc[h] = fmaf(pe[u], Bp[(z4 + u) * 8 + h], acc[h]);
  }
#pragma unroll
  for (int h = 0; h < 8; ++h)
    bias[(size_t)h * 65536 + ij] = f2bf(acc[h]);
}

// ---------------------------------------------------------------------------
// bf16 MFMA GEMM, 128x128 tile, BK=32, 4 waves, double-buffered LDS with
// counted vmcnt(4) prefetch (T3-minimum 2-phase; raw s_barrier, no vmcnt(0)
// drain in steady state).
// A [M][K] bf16, Bt [N][K] bf16 (B transposed).
// MODE 0: n<256 -> sigmoid -> gate (ld 256); n in [256,512) -> q * QSCALE;
//         n>=256 stored to qkv (ld 768). bf16 out.
// MODE 1: f32 C [M][N].
// ---------------------------------------------------------------------------
template <int MODE>
__global__ __launch_bounds__(256) void gemm_bf16(
    const short* __restrict__ A, const short* __restrict__ Bt,
    void* __restrict__ C0, void* __restrict__ C1, int M, int N, int K) {
  __shared__ short As[2][128 * 32];
  __shared__ short Bs[2][128 * 32];
  const int tid = threadIdx.x;
  const int lane = tid & 63, w = tid >> 6;
  const int l15 = lane & 15, l4 = lane >> 4;
  const int m0 = blockIdx.y * 128, n0 = blockIdx.x * 128;
  const int wm = (w >> 1) * 64, wn = (w & 1) * 64;

  f32x4 acc[4][4];
#pragma unroll
  for (int i = 0; i < 4; ++i)
#pragma unroll
    for (int j = 0; j < 4; ++j) acc[i][j] = (f32x4)(0.0f);

  // staging: wave w fills rows [w*32, w*32+32) of As and Bs.
  // one gl_lds16 = 64 lanes * 16B = 1KB = 16 rows (4 lanes/row, linear dest)
  const int srow = w * 32 + (lane >> 2);
  const int scol = (lane & 3) * 8;

  auto stage = [&](int buf, int k0) {
    gl_lds16(A + (size_t)(m0 + srow) * K + k0 + scol, &As[buf][(w * 32) * 32]);
    gl_lds16(A + (size_t)(m0 + srow + 16) * K + k0 + scol,
             &As[buf][(w * 32 + 16) * 32]);
    gl_lds16(Bt + (size_t)(n0 + srow) * K + k0 + scol, &Bs[buf][(w * 32) * 32]);
    gl_lds16(Bt + (size_t)(n0 + srow + 16) * K + k0 + scol,
             &Bs[buf][(w * 32 + 16) * 32]);
  };

  const int NT = K >> 5;
  stage(0, 0);
  for (int t = 0; t < NT; ++t) {
    const int cur = t & 1;
    if (t + 1 < NT) {
      stage(cur ^ 1, (t + 1) << 5);
      asm volatile("s_waitcnt vmcnt(4)" ::: "memory");  // wait buf[cur] only
    } else {
      asm volatile("s_waitcnt vmcnt(0)" ::: "memory");
    }
    __builtin_amdgcn_s_barrier();
    __builtin_amdgcn_sched_barrier(0);
#pragma unroll
    for (int nf = 0; nf < 4; ++nf) {
      bf8 bfr = *(const bf8*)(&Bs[cur][(wn + nf * 16 + l15) * 32 + l4 * 8]);
#pragma unroll
      for (int mf = 0; mf < 4; ++mf) {
        bf8 afr = *(const bf8*)(&As[cur][(wm + mf * 16 + l15) * 32 + l4 * 8]);
        acc[mf][nf] =
            __builtin_amdgcn_mfma_f32_16x16x32_bf16(afr, bfr, acc[mf][nf], 0, 0, 0);
      }
    }
    __builtin_amdgcn_sched_barrier(0);
    __builtin_amdgcn_s_barrier();  // compute done before next stage overwrites
  }

#pragma unroll
  for (int mf = 0; mf < 4; ++mf)
#pragma unroll
    for (int nf = 0; nf < 4; ++nf)
#pragma unroll
      for (int r = 0; r < 4; ++r) {
        const int m = m0 + wm + mf * 16 + l4 * 4 + r;
        const int n = n0 + wn + nf * 16 + l15;
        float v = acc[mf][nf][r];
        if (MODE == 0) {
          if (n < 256) {
            ((short*)C0)[(size_t)m * 256 + n] = f2bf(1.0f / (1.0f + __expf(-v)));
          } else {
            if (n < 512) v *= QSCALE;  // prescale q so attn uses exp2 directly
            ((short*)C1)[(size_t)m * 768 + (n - 256)] = f2bf(v);
          }
        } else {
          ((float*)C0)[(size_t)m * N + n] = v;
        }
      }
}

// ---------------------------------------------------------------------------
// MFMA attention per (s,h). 4 waves; wave w owns q-rows [w*64, w*64+64).
// Plds is WAVE-PRIVATE -> no barriers in the k-loop (intra-wave lgkmcnt
// ordering suffices); waves run free to hide each other's latency.
// Q was prescaled by SCALE*log2e -> softmax exp via exp2f, no mul.
//   attendg = ( exp2(S')·V / l + B·V ) * gate,  all contractions via MFMA.
// ---------------------------------------------------------------------------
__global__ __launch_bounds__(256) void attn_mfma(
    const short* __restrict__ qkv,    // [32768][768] bf16 (q prescaled)
    const short* __restrict__ bias,   // [8][256][256] bf16
    const short* __restrict__ gate,   // [32768][256] bf16
    short* __restrict__ attendg) {    // [32768][256] bf16 out
  const int s = blockIdx.x >> 3;
  const int h = blockIdx.x & 7;
  const int tid = threadIdx.x;
  const int lane = tid & 63, w = tid >> 6;
  const int l15 = lane & 15, l4 = lane >> 4;

  __shared__ short Vt[32][264];      // V^T (16.9 KB)
  __shared__ short Plds[4][64][68];  // per-wave P chunk, pad 68 (34.8 KB)
                                     // total 50.5 KB -> 3 blocks/CU

  // ---- stage V^T: thread t loads V row t (32 bf16), writes column t
  {
    const short* vrow = qkv + (size_t)(s * 256 + tid) * 768 + 512 + h * 32;
    short tmp[32];
    *(int4*)(tmp +  0) = *(const int4*)(vrow +  0);
    *(int4*)(tmp +  8) = *(const int4*)(vrow +  8);
    *(int4*)(tmp + 16) = *(const int4*)(vrow + 16);
    *(int4*)(tmp + 24) = *(const int4*)(vrow + 24);
#pragma unroll
    for (int c = 0; c < 32; ++c) Vt[c][tid] = tmp[c];
  }

  // ---- Q fragments in registers (reused across all k-chunks)
  bf8 qf[4];
  const int q0 = w * 64;
#pragma unroll
  for (int mf = 0; mf < 4; ++mf)
    qf[mf] = *(const bf8*)(qkv + (size_t)(s * 256 + q0 + mf * 16 + l15) * 768 +
                           h * 32 + l4 * 8);

  __syncthreads();  // Vt ready (only cross-wave dependency)

  f32x4 o1[4][2], o2[4][2];
  float lsum[16];
#pragma unroll
  for (int mf = 0; mf < 4; ++mf)
#pragma unroll
    for (int nf = 0; nf < 2; ++nf) {
      o1[mf][nf] = (f32x4)(0.0f);
      o2[mf][nf] = (f32x4)(0.0f);
    }
#pragma unroll
  for (int i = 0; i < 16; ++i) lsum[i] = 0.0f;

  for (int kb = 0; kb < 4; ++kb) {
    // ---- S chunk = Q' · K^T (64q x 64k per wave), K frags from global
    f32x4 sa[4][4];
    __builtin_amdgcn_s_setprio(1);
#pragma unroll
    for (int nf = 0; nf < 4; ++nf) {
      bf8 kf = *(const bf8*)(qkv +
                             (size_t)(s * 256 + kb * 64 + nf * 16 + l15) * 768 +
                             256 + h * 32 + l4 * 8);
#pragma unroll
      for (int mf = 0; mf < 4; ++mf)
        sa[mf][nf] =
            __builtin_amdgcn_mfma_f32_16x16x32_bf16(qf[mf], kf, (f32x4)(0.0f), 0, 0, 0);
    }
    __builtin_amdgcn_s_setprio(0);

    // ---- exp2 + row-sum partials + spill P (bf16) to wave-private LDS
#pragma unroll
    for (int mf = 0; mf < 4; ++mf)
#pragma unroll
      for (int nf = 0; nf < 4; ++nf)
#pragma unroll
        for (int r = 0; r < 4; ++r) {
          float e = exp2f(sa[mf][nf][r]);
          lsum[mf * 4 + r] += e;
          Plds[w][mf * 16 + l4 * 4 + r][nf * 16 + l15] = f2bf(e);
        }
    // no barrier: Plds[w] is wave-private; lgkmcnt orders write->read

    // ---- PV (o1) and B·V (o2); bias frags direct from global
    __builtin_amdgcn_s_setprio(1);
#pragma unroll
    for (int ks = 0; ks < 2; ++ks) {
      bf8 vf[2];
#pragma unroll
      for (int nf = 0; nf < 2; ++nf)
        vf[nf] = *(const bf8*)(&Vt[nf * 16 + l15][kb * 64 + ks * 32 + l4 * 8]);
#pragma unroll
      for (int mf = 0; mf < 4; ++mf) {
        bf8 pf = *(const bf8*)(&Plds[w][mf * 16 + l15][ks * 32 + l4 * 8]);
        bf8 bfr = *(const bf8*)(bias + ((size_t)h * 256 + q0 + mf * 16 + l15) * 256 +
                                kb * 64 + ks * 32 + l4 * 8);
#pragma unroll
        for (int nf = 0; nf < 2; ++nf) {
          o1[mf][nf] = __builtin_amdgcn_mfma_f32_16x16x32_bf16(pf, vf[nf], o1[mf][nf], 0, 0, 0);
          o2[mf][nf] = __builtin_amdgcn_mfma_f32_16x16x32_bf16(bfr, vf[nf], o2[mf][nf], 0, 0, 0);
        }
      }
    }
    __builtin_amdgcn_s_setprio(0);
  }

  // ---- row sums: reduce over the 16 lanes sharing each q-row set
#pragma unroll
  for (int i = 0; i < 16; ++i) {
    float v = lsum[i];
    v += __shfl_xor(v, 1);
    v += __shfl_xor(v, 2);
    v += __shfl_xor(v, 4);
    v += __shfl_xor(v, 8);
    lsum[i] = 1.0f / v;
  }

  // ---- epilogue: normalize, add bias term, gate, store bf16
#pragma unroll
  for (int mf = 0; mf < 4; ++mf)
#pragma unroll
    for (int nf = 0; nf < 2; ++nf)
#pragma unroll
      for (int r = 0; r < 4; ++r) {
        const int q = q0 + mf * 16 + l4 * 4 + r;
        const int c = nf * 16 + l15;
        const size_t off = (size_t)(s * 256 + q) * 256 + h * 32 + c;
        float val = o1[mf][nf][r] * lsum[mf * 4 + r] + o2[mf][nf][r];
        attendg[off] = f2bf(val * bf2f(gate[off]));
      }
}

// ---------------------------------------------------------------------------
extern "C" void kernel_launch(void* const* d_in, const int* in_sizes, int n_in,
                              void* d_out, int out_size, void* d_ws,
                              size_t ws_size, hipStream_t stream) {
  const float* msa    = (const float*)d_in[0];  // [32768][256]
  const float* pair   = (const float*)d_in[1];  // [65536][128]
  const float* gate_w = (const float*)d_in[2];  // [256][256]
  const float* qkv_w  = (const float*)d_in[3];  // [256][768]
  const float* out_w  = (const float*)d_in[4];  // [256][256]
  const float* bias_w = (const float*)d_in[5];  // [128][8]
  float* out = (float*)d_out;                   // [32768][256] f32

  char* ws = (char*)d_ws;
  short* qkv_bf  = (short*)(ws);                 // 50,331,648 B
  short* msa_bf  = (short*)(ws + 50331648);      // 16,777,216 B
  short* gate_bf = (short*)(ws + 67108864);      // 16,777,216 B
  short* attendg = (short*)(ws + 83886080);      // 16,777,216 B
  short* bias_bf = (short*)(ws + 100663296);     //  1,048,576 B
  short* wcat_t  = (short*)(ws + 101711872);     //    524,288 B
  short* owt     = (short*)(ws + 102236160);     //    131,072 B

  const int M = 32768;

  convert_msa<<<2048, 256, 0, stream>>>(msa, msa_bf, M * 256 / 4);
  prep_w<<<1280, 256, 0, stream>>>(gate_w, qkv_w, out_w, wcat_t, owt);
  bias_kernel<<<256, 256, 0, stream>>>(pair, bias_w, bias_bf);

  // gate|qkv fused GEMM: [M,256] @ [256,1024]
  gemm_bf16<0><<<dim3(8, M / 128), 256, 0, stream>>>(
      msa_bf, wcat_t, gate_bf, qkv_bf, M, 1024, 256);

  attn_mfma<<<1024, 256, 0, stream>>>(qkv_bf, bias_bf, gate_bf, attendg);

  // out GEMM: [M,256] @ [256,256] -> f32
  gemm_bf16<1><<<dim3(2, M / 128), 256, 0, stream>>>(
      attendg, owt, out, nullptr, M, 256, 256);
}

// Round 8
// 228.958 us; speedup vs baseline: 3.0969x; 1.0345x over previous
//
#include <hip/hip_runtime.h>
#include <hip/hip_bf16.h>
#include <stdint.h>

#define QSCALE 0.2550348552724541f  // (1/sqrt(32)) * log2(e), folded into q

typedef short bf8 __attribute__((ext_vector_type(8)));    // 8 bf16 (4 VGPR)
typedef float f32x4 __attribute__((ext_vector_type(4)));  // MFMA acc

__device__ __forceinline__ short f2bf(float f) {
  unsigned u = __builtin_bit_cast(unsigned, f);
  u = (u + 0x7FFFu + ((u >> 16) & 1u)) >> 16;  // RNE
  return (short)u;
}
__device__ __forceinline__ float bf2f(short s) {
  return __builtin_bit_cast(float, ((unsigned)(unsigned short)s) << 16);
}
__device__ __forceinline__ void gl_lds16(const void* g, void* l) {
  __builtin_amdgcn_global_load_lds(
      (const __attribute__((address_space(1))) unsigned int*)g,
      (__attribute__((address_space(3))) unsigned int*)l, 16, 0, 0);
}

// ---------------------------------------------------------------------------
// msa f32 -> bf16, vectorized (float4 in, short4 out)
// ---------------------------------------------------------------------------
__global__ __launch_bounds__(256) void convert_msa(
    const float* __restrict__ in, short* __restrict__ out, int n4) {
  int i = blockIdx.x * 256 + threadIdx.x;
  const int stride = gridDim.x * 256;
  for (; i < n4; i += stride) {
    float4 v = ((const float4*)in)[i];
    short4 o;
    o.x = f2bf(v.x); o.y = f2bf(v.y); o.z = f2bf(v.z); o.w = f2bf(v.w);
    ((short4*)out)[i] = o;
  }
}

// ---------------------------------------------------------------------------
// weights: wcat_t[n][k] = (n<256? gate_w[k][n] : qkv_w[k][n-256]) as bf16
//          owt[n][k]    = out_w[k][n] as bf16
// ---------------------------------------------------------------------------
__global__ __launch_bounds__(256) void prep_w(
    const float* __restrict__ gw, const float* __restrict__ qw,
    const float* __restrict__ ow, short* __restrict__ wcat,
    short* __restrict__ owt) {
  int i = blockIdx.x * 256 + threadIdx.x;  // 0..327679
  if (i < 262144) {
    int n = i >> 8, k = i & 255;
    wcat[i] = f2bf(n < 256 ? gw[k * 256 + n] : qw[k * 768 + (n - 256)]);
  } else if (i < 327680) {
    int j = i - 262144;
    int n = j >> 8, k = j & 255;
    owt[j] = f2bf(ow[k * 256 + n]);
  }
}

// ---------------------------------------------------------------------------
// bias_bf[h][i][j] = sum_z pair[i][j][z] * bias_w[z][h]   (bf16 out)
// ---------------------------------------------------------------------------
__global__ __launch_bounds__(256) void bias_kernel(
    const float* __restrict__ pair, const float* __restrict__ bias_w,
    short* __restrict__ bias) {
  __shared__ float Bp[1024];  // [z][h] 128x8
  const int t = threadIdx.x;
  for (int i = t; i < 1024; i += 256) Bp[i] = bias_w[i];
  __syncthreads();

  const int ij = blockIdx.x * 256 + t;
  const float* pr = pair + (size_t)ij * 128;

  float acc[8] = {};
  for (int z4 = 0; z4 < 128; z4 += 4) {
    float4 pv = *(const float4*)&pr[z4];
    const float pe[4] = {pv.x, pv.y, pv.z, pv.w};
#pragma unroll
    for (int u = 0; u < 4; ++u)
#pragma unroll
      for (int h = 0; h < 8; ++h)
        acc[h] = fmaf(pe[u], Bp[(z4 + u) * 8 + h], acc[h]);
  }
#pragma unroll
  for (int h = 0; h < 8; ++h)
    bias[(size_t)h * 65536 + ij] = f2bf(acc[h]);
}

// ---------------------------------------------------------------------------
// bf16 MFMA GEMM, 128x128 tile, BK=32, 4 waves (each 64x64), global_load_lds.
// Round-5 proven single-buffer structure (compiler schedules the interleave;
// no sched_barrier pinning — m141 lesson).
// GRID IS TRANSPOSED: blockIdx.x = m-tile, blockIdx.y = n-tile, so the
// n-tiles sharing one A-panel land on ONE XCD (id%8 = x%8) -> A fetched
// once per XCD instead of 8x.
// A [M][K] bf16, Bt [N][K] bf16 (B transposed).
// MODE 0: n<256 -> sigmoid -> gate (ld 256); n in [256,512) -> q * QSCALE;
//         n>=256 stored to qkv (ld 768). bf16 out.
// MODE 1: f32 C [M][N].
// ---------------------------------------------------------------------------
template <int MODE>
__global__ __launch_bounds__(256) void gemm_bf16(
    const short* __restrict__ A, const short* __restrict__ Bt,
    void* __restrict__ C0, void* __restrict__ C1, int M, int N, int K) {
  __shared__ short As[128 * 32];
  __shared__ short Bs[128 * 32];
  const int tid = threadIdx.x;
  const int lane = tid & 63, w = tid >> 6;
  const int l15 = lane & 15, l4 = lane >> 4;
  const int m0 = blockIdx.x * 128, n0 = blockIdx.y * 128;  // transposed grid
  const int wm = (w >> 1) * 64, wn = (w & 1) * 64;

  f32x4 acc[4][4];
#pragma unroll
  for (int i = 0; i < 4; ++i)
#pragma unroll
    for (int j = 0; j < 4; ++j) acc[i][j] = (f32x4)(0.0f);

  // staging: wave w fills rows [w*32, w*32+32) of As and Bs.
  // one gl_lds16 call = 64 lanes * 16B = 1KB = 16 rows (4 lanes/row)
  const int srow = w * 32 + (lane >> 2);
  const int scol = (lane & 3) * 8;  // elem offset within 32-elem row chunk

  for (int k0 = 0; k0 < K; k0 += 32) {
    __syncthreads();  // previous compute done before overwriting LDS
    gl_lds16(A + (size_t)(m0 + srow) * K + k0 + scol, &As[(w * 32) * 32]);
    gl_lds16(A + (size_t)(m0 + srow + 16) * K + k0 + scol, &As[(w * 32 + 16) * 32]);
    gl_lds16(Bt + (size_t)(n0 + srow) * K + k0 + scol, &Bs[(w * 32) * 32]);
    gl_lds16(Bt + (size_t)(n0 + srow + 16) * K + k0 + scol, &Bs[(w * 32 + 16) * 32]);
    __syncthreads();  // implicit vmcnt(0) drain makes LDS data visible
#pragma unroll
    for (int nf = 0; nf < 4; ++nf) {
      bf8 bfr = *(const bf8*)(&Bs[(wn + nf * 16 + l15) * 32 + l4 * 8]);
#pragma unroll
      for (int mf = 0; mf < 4; ++mf) {
        bf8 afr = *(const bf8*)(&As[(wm + mf * 16 + l15) * 32 + l4 * 8]);
        acc[mf][nf] =
            __builtin_amdgcn_mfma_f32_16x16x32_bf16(afr, bfr, acc[mf][nf], 0, 0, 0);
      }
    }
  }

#pragma unroll
  for (int mf = 0; mf < 4; ++mf)
#pragma unroll
    for (int nf = 0; nf < 4; ++nf)
#pragma unroll
      for (int r = 0; r < 4; ++r) {
        const int m = m0 + wm + mf * 16 + l4 * 4 + r;
        const int n = n0 + wn + nf * 16 + l15;
        float v = acc[mf][nf][r];
        if (MODE == 0) {
          if (n < 256) {
            ((short*)C0)[(size_t)m * 256 + n] = f2bf(1.0f / (1.0f + __expf(-v)));
          } else {
            if (n < 512) v *= QSCALE;  // prescale q so attn uses exp2 directly
            ((short*)C1)[(size_t)m * 768 + (n - 256)] = f2bf(v);
          }
        } else {
          ((float*)C0)[(size_t)m * N + n] = v;
        }
      }
}

// ---------------------------------------------------------------------------
// MFMA attention per (s,h). 4 waves; wave w owns q-rows [w*64, w*64+64).
// Plds is WAVE-PRIVATE -> no barriers in the k-loop (intra-wave lgkmcnt
// ordering suffices); waves run free to hide each other's latency.
// Q was prescaled by SCALE*log2e -> softmax exp via exp2f, no mul.
//   attendg = ( exp2(S')·V / l + B·V ) * gate,  all contractions via MFMA.
// ---------------------------------------------------------------------------
__global__ __launch_bounds__(256) void attn_mfma(
    const short* __restrict__ qkv,    // [32768][768] bf16 (q prescaled)
    const short* __restrict__ bias,   // [8][256][256] bf16
    const short* __restrict__ gate,   // [32768][256] bf16
    short* __restrict__ attendg) {    // [32768][256] bf16 out
  const int s = blockIdx.x >> 3;
  const int h = blockIdx.x & 7;
  const int tid = threadIdx.x;
  const int lane = tid & 63, w = tid >> 6;
  const int l15 = lane & 15, l4 = lane >> 4;

  __shared__ short Vt[32][264];      // V^T (16.9 KB)
  __shared__ short Plds[4][64][68];  // per-wave P chunk, pad 68 (34.8 KB)
                                     // total 50.5 KB -> 3 blocks/CU

  // ---- stage V^T: thread t loads V row t (32 bf16), writes column t
  {
    const short* vrow = qkv + (size_t)(s * 256 + tid) * 768 + 512 + h * 32;
    short tmp[32];
    *(int4*)(tmp +  0) = *(const int4*)(vrow +  0);
    *(int4*)(tmp +  8) = *(const int4*)(vrow +  8);
    *(int4*)(tmp + 16) = *(const int4*)(vrow + 16);
    *(int4*)(tmp + 24) = *(const int4*)(vrow + 24);
#pragma unroll
    for (int c = 0; c < 32; ++c) Vt[c][tid] = tmp[c];
  }

  // ---- Q fragments in registers (reused across all k-chunks)
  bf8 qf[4];
  const int q0 = w * 64;
#pragma unroll
  for (int mf = 0; mf < 4; ++mf)
    qf[mf] = *(const bf8*)(qkv + (size_t)(s * 256 + q0 + mf * 16 + l15) * 768 +
                           h * 32 + l4 * 8);

  __syncthreads();  // Vt ready (only cross-wave dependency)

  f32x4 o1[4][2], o2[4][2];
  float lsum[16];
#pragma unroll
  for (int mf = 0; mf < 4; ++mf)
#pragma unroll
    for (int nf = 0; nf < 2; ++nf) {
      o1[mf][nf] = (f32x4)(0.0f);
      o2[mf][nf] = (f32x4)(0.0f);
    }
#pragma unroll
  for (int i = 0; i < 16; ++i) lsum[i] = 0.0f;

  for (int kb = 0; kb < 4; ++kb) {
    // ---- S chunk = Q' · K^T (64q x 64k per wave), K frags from global
    f32x4 sa[4][4];
    __builtin_amdgcn_s_setprio(1);
#pragma unroll
    for (int nf = 0; nf < 4; ++nf) {
      bf8 kf = *(const bf8*)(qkv +
                             (size_t)(s * 256 + kb * 64 + nf * 16 + l15) * 768 +
                             256 + h * 32 + l4 * 8);
#pragma unroll
      for (int mf = 0; mf < 4; ++mf)
        sa[mf][nf] =
            __builtin_amdgcn_mfma_f32_16x16x32_bf16(qf[mf], kf, (f32x4)(0.0f), 0, 0, 0);
    }
    __builtin_amdgcn_s_setprio(0);

    // ---- exp2 + row-sum partials + spill P (bf16) to wave-private LDS
#pragma unroll
    for (int mf = 0; mf < 4; ++mf)
#pragma unroll
      for (int nf = 0; nf < 4; ++nf)
#pragma unroll
        for (int r = 0; r < 4; ++r) {
          float e = exp2f(sa[mf][nf][r]);
          lsum[mf * 4 + r] += e;
          Plds[w][mf * 16 + l4 * 4 + r][nf * 16 + l15] = f2bf(e);
        }
    // no barrier: Plds[w] is wave-private; lgkmcnt orders write->read

    // ---- PV (o1) and B·V (o2); bias frags direct from global
    __builtin_amdgcn_s_setprio(1);
#pragma unroll
    for (int ks = 0; ks < 2; ++ks) {
      bf8 vf[2];
#pragma unroll
      for (int nf = 0; nf < 2; ++nf)
        vf[nf] = *(const bf8*)(&Vt[nf * 16 + l15][kb * 64 + ks * 32 + l4 * 8]);
#pragma unroll
      for (int mf = 0; mf < 4; ++mf) {
        bf8 pf = *(const bf8*)(&Plds[w][mf * 16 + l15][ks * 32 + l4 * 8]);
        bf8 bfr = *(const bf8*)(bias + ((size_t)h * 256 + q0 + mf * 16 + l15) * 256 +
                                kb * 64 + ks * 32 + l4 * 8);
#pragma unroll
        for (int nf = 0; nf < 2; ++nf) {
          o1[mf][nf] = __builtin_amdgcn_mfma_f32_16x16x32_bf16(pf, vf[nf], o1[mf][nf], 0, 0, 0);
          o2[mf][nf] = __builtin_amdgcn_mfma_f32_16x16x32_bf16(bfr, vf[nf], o2[mf][nf], 0, 0, 0);
        }
      }
    }
    __builtin_amdgcn_s_setprio(0);
  }

  // ---- row sums: reduce over the 16 lanes sharing each q-row set
#pragma unroll
  for (int i = 0; i < 16; ++i) {
    float v = lsum[i];
    v += __shfl_xor(v, 1);
    v += __shfl_xor(v, 2);
    v += __shfl_xor(v, 4);
    v += __shfl_xor(v, 8);
    lsum[i] = 1.0f / v;
  }

  // ---- epilogue: normalize, add bias term, gate, store bf16
#pragma unroll
  for (int mf = 0; mf < 4; ++mf)
#pragma unroll
    for (int nf = 0; nf < 2; ++nf)
#pragma unroll
      for (int r = 0; r < 4; ++r) {
        const int q = q0 + mf * 16 + l4 * 4 + r;
        const int c = nf * 16 + l15;
        const size_t off = (size_t)(s * 256 + q) * 256 + h * 32 + c;
        float val = o1[mf][nf][r] * lsum[mf * 4 + r] + o2[mf][nf][r];
        attendg[off] = f2bf(val * bf2f(gate[off]));
      }
}

// ---------------------------------------------------------------------------
extern "C" void kernel_launch(void* const* d_in, const int* in_sizes, int n_in,
                              void* d_out, int out_size, void* d_ws,
                              size_t ws_size, hipStream_t stream) {
  const float* msa    = (const float*)d_in[0];  // [32768][256]
  const float* pair   = (const float*)d_in[1];  // [65536][128]
  const float* gate_w = (const float*)d_in[2];  // [256][256]
  const float* qkv_w  = (const float*)d_in[3];  // [256][768]
  const float* out_w  = (const float*)d_in[4];  // [256][256]
  const float* bias_w = (const float*)d_in[5];  // [128][8]
  float* out = (float*)d_out;                   // [32768][256] f32

  char* ws = (char*)d_ws;
  short* qkv_bf  = (short*)(ws);                 // 50,331,648 B
  short* msa_bf  = (short*)(ws + 50331648);      // 16,777,216 B
  short* gate_bf = (short*)(ws + 67108864);      // 16,777,216 B
  short* attendg = (short*)(ws + 83886080);      // 16,777,216 B
  short* bias_bf = (short*)(ws + 100663296);     //  1,048,576 B
  short* wcat_t  = (short*)(ws + 101711872);     //    524,288 B
  short* owt     = (short*)(ws + 102236160);     //    131,072 B

  const int M = 32768;

  convert_msa<<<2048, 256, 0, stream>>>(msa, msa_bf, M * 256 / 4);
  prep_w<<<1280, 256, 0, stream>>>(gate_w, qkv_w, out_w, wcat_t, owt);
  bias_kernel<<<256, 256, 0, stream>>>(pair, bias_w, bias_bf);

  // gate|qkv fused GEMM: [M,256] @ [256,1024]  (grid transposed: x=m, y=n)
  gemm_bf16<0><<<dim3(M / 128, 8), 256, 0, stream>>>(
      msa_bf, wcat_t, gate_bf, qkv_bf, M, 1024, 256);

  attn_mfma<<<1024, 256, 0, stream>>>(qkv_bf, bias_bf, gate_bf, attendg);

  // out GEMM: [M,256] @ [256,256] -> f32  (grid transposed)
  gemm_bf16<1><<<dim3(M / 128, 2), 256, 0, stream>>>(
      attendg, owt, out, nullptr, M, 256, 256);
}

// Round 9
// 215.139 us; speedup vs baseline: 3.2958x; 1.0642x over previous
//
#include <hip/hip_runtime.h>
#include <hip/hip_bf16.h>
#include <stdint.h>

#define QSCALE 0.2550348552724541f  // (1/sqrt(32)) * log2(e), folded into q

typedef short bf8 __attribute__((ext_vector_type(8)));    // 8 bf16 (4 VGPR)
typedef float f32x4 __attribute__((ext_vector_type(4)));  // MFMA acc

__device__ __forceinline__ short f2bf(float f) {
  unsigned u = __builtin_bit_cast(unsigned, f);
  u = (u + 0x7FFFu + ((u >> 16) & 1u)) >> 16;  // RNE
  return (short)u;
}
__device__ __forceinline__ float bf2f(short s) {
  return __builtin_bit_cast(float, ((unsigned)(unsigned short)s) << 16);
}
__device__ __forceinline__ void gl_lds16(const void* g, void* l) {
  __builtin_amdgcn_global_load_lds(
      (const __attribute__((address_space(1))) unsigned int*)g,
      (__attribute__((address_space(3))) unsigned int*)l, 16, 0, 0);
}

// ---------------------------------------------------------------------------
// msa f32 -> bf16, vectorized (float4 in, short4 out)
// ---------------------------------------------------------------------------
__global__ __launch_bounds__(256) void convert_msa(
    const float* __restrict__ in, short* __restrict__ out, int n4) {
  int i = blockIdx.x * 256 + threadIdx.x;
  const int stride = gridDim.x * 256;
  for (; i < n4; i += stride) {
    float4 v = ((const float4*)in)[i];
    short4 o;
    o.x = f2bf(v.x); o.y = f2bf(v.y); o.z = f2bf(v.z); o.w = f2bf(v.w);
    ((short4*)out)[i] = o;
  }
}

// ---------------------------------------------------------------------------
// Fused prep: blocks 0..255   -> bias_bf[h][i][j] = pair[i][j][:] . bias_w[:][h]
//             blocks 256..1535-> wcat_t / owt weight transposes (bf16)
// ---------------------------------------------------------------------------
__global__ __launch_bounds__(256) void prep_all(
    const float* __restrict__ pair, const float* __restrict__ bias_w,
    short* __restrict__ bias, const float* __restrict__ gw,
    const float* __restrict__ qw, const float* __restrict__ ow,
    short* __restrict__ wcat, short* __restrict__ owt) {
  const int b = blockIdx.x;
  const int t = threadIdx.x;
  if (b < 256) {
    __shared__ float Bp[1024];  // [z][h] 128x8
    for (int i = t; i < 1024; i += 256) Bp[i] = bias_w[i];
    __syncthreads();

    const int ij = b * 256 + t;
    const float* pr = pair + (size_t)ij * 128;

    float acc[8] = {};
    for (int z4 = 0; z4 < 128; z4 += 4) {
      float4 pv = *(const float4*)&pr[z4];
      const float pe[4] = {pv.x, pv.y, pv.z, pv.w};
#pragma unroll
      for (int u = 0; u < 4; ++u)
#pragma unroll
        for (int h = 0; h < 8; ++h)
          acc[h] = fmaf(pe[u], Bp[(z4 + u) * 8 + h], acc[h]);
    }
#pragma unroll
    for (int h = 0; h < 8; ++h)
      bias[(size_t)h * 65536 + ij] = f2bf(acc[h]);
  } else {
    int i = (b - 256) * 256 + t;  // 0..327679
    if (i < 262144) {
      int n = i >> 8, k = i & 255;
      wcat[i] = f2bf(n < 256 ? gw[k * 256 + n] : qw[k * 768 + (n - 256)]);
    } else {
      int j = i - 262144;
      int n = j >> 8, k = j & 255;
      owt[j] = f2bf(ow[k * 256 + n]);
    }
  }
}

// ---------------------------------------------------------------------------
// bf16 MFMA GEMM, 128x128 tile, BK=32, 4 waves (each 64x64), global_load_lds.
// Proven single-buffer structure; transposed grid (x=m-tile, y=n-tile) so
// same-A-panel blocks land on one XCD (A fetched ~once per XCD).
// MODE 0: n<256 -> sigmoid -> gate (ld 256); n in [256,512) -> q * QSCALE;
//         n>=256 stored to qkv (ld 768). bf16 out.
// MODE 1: f32 C [M][N].
// ---------------------------------------------------------------------------
template <int MODE>
__global__ __launch_bounds__(256) void gemm_bf16(
    const short* __restrict__ A, const short* __restrict__ Bt,
    void* __restrict__ C0, void* __restrict__ C1, int M, int N, int K) {
  __shared__ short As[128 * 32];
  __shared__ short Bs[128 * 32];
  const int tid = threadIdx.x;
  const int lane = tid & 63, w = tid >> 6;
  const int l15 = lane & 15, l4 = lane >> 4;
  const int m0 = blockIdx.x * 128, n0 = blockIdx.y * 128;  // transposed grid
  const int wm = (w >> 1) * 64, wn = (w & 1) * 64;

  f32x4 acc[4][4];
#pragma unroll
  for (int i = 0; i < 4; ++i)
#pragma unroll
    for (int j = 0; j < 4; ++j) acc[i][j] = (f32x4)(0.0f);

  const int srow = w * 32 + (lane >> 2);
  const int scol = (lane & 3) * 8;

  for (int k0 = 0; k0 < K; k0 += 32) {
    __syncthreads();  // previous compute done before overwriting LDS
    gl_lds16(A + (size_t)(m0 + srow) * K + k0 + scol, &As[(w * 32) * 32]);
    gl_lds16(A + (size_t)(m0 + srow + 16) * K + k0 + scol, &As[(w * 32 + 16) * 32]);
    gl_lds16(Bt + (size_t)(n0 + srow) * K + k0 + scol, &Bs[(w * 32) * 32]);
    gl_lds16(Bt + (size_t)(n0 + srow + 16) * K + k0 + scol, &Bs[(w * 32 + 16) * 32]);
    __syncthreads();  // implicit vmcnt(0) drain makes LDS data visible
#pragma unroll
    for (int nf = 0; nf < 4; ++nf) {
      bf8 bfr = *(const bf8*)(&Bs[(wn + nf * 16 + l15) * 32 + l4 * 8]);
#pragma unroll
      for (int mf = 0; mf < 4; ++mf) {
        bf8 afr = *(const bf8*)(&As[(wm + mf * 16 + l15) * 32 + l4 * 8]);
        acc[mf][nf] =
            __builtin_amdgcn_mfma_f32_16x16x32_bf16(afr, bfr, acc[mf][nf], 0, 0, 0);
      }
    }
  }

#pragma unroll
  for (int mf = 0; mf < 4; ++mf)
#pragma unroll
    for (int nf = 0; nf < 4; ++nf)
#pragma unroll
      for (int r = 0; r < 4; ++r) {
        const int m = m0 + wm + mf * 16 + l4 * 4 + r;
        const int n = n0 + wn + nf * 16 + l15;
        float v = acc[mf][nf][r];
        if (MODE == 0) {
          if (n < 256) {
            ((short*)C0)[(size_t)m * 256 + n] = f2bf(1.0f / (1.0f + __expf(-v)));
          } else {
            if (n < 512) v *= QSCALE;  // prescale q so attn uses exp2 directly
            ((short*)C1)[(size_t)m * 768 + (n - 256)] = f2bf(v);
          }
        } else {
          ((float*)C0)[(size_t)m * N + n] = v;
        }
      }
}

// ---------------------------------------------------------------------------
// MFMA attention per (s,h). 8 waves x 512 threads; wave w owns q-rows
// [w*32, w*32+32). Same per-block LDS as the 4-wave version (Plds scales
// with q-rows, not waves) -> 2 blocks/CU (VGPR-bound) = 16 waves/CU steady,
// grid 1024 = exactly 2 phases of 2 blocks/CU (no solo tail).
// Plds is WAVE-PRIVATE -> no barriers in the k-loop.
// Q prescaled by SCALE*log2e -> softmax exp via exp2f.
//   attendg = ( exp2(S')·V / l + B·V ) * gate,  all contractions via MFMA.
// ---------------------------------------------------------------------------
__global__ __launch_bounds__(512, 4) void attn_mfma(
    const short* __restrict__ qkv,    // [32768][768] bf16 (q prescaled)
    const short* __restrict__ bias,   // [8][256][256] bf16
    const short* __restrict__ gate,   // [32768][256] bf16
    short* __restrict__ attendg) {    // [32768][256] bf16 out
  const int s = blockIdx.x >> 3;
  const int h = blockIdx.x & 7;
  const int tid = threadIdx.x;
  const int lane = tid & 63, w = tid >> 6;  // w 0..7
  const int l15 = lane & 15, l4 = lane >> 4;

  __shared__ short Vt[32][264];      // V^T (16.9 KB)
  __shared__ short Plds[8][32][68];  // per-wave P chunk (34.8 KB)

  // ---- stage V^T: threads 0..255 load V row t (32 bf16), write column t
  if (tid < 256) {
    const short* vrow = qkv + (size_t)(s * 256 + tid) * 768 + 512 + h * 32;
    short tmp[32];
    *(int4*)(tmp +  0) = *(const int4*)(vrow +  0);
    *(int4*)(tmp +  8) = *(const int4*)(vrow +  8);
    *(int4*)(tmp + 16) = *(const int4*)(vrow + 16);
    *(int4*)(tmp + 24) = *(const int4*)(vrow + 24);
#pragma unroll
    for (int c = 0; c < 32; ++c) Vt[c][tid] = tmp[c];
  }

  // ---- Q fragments in registers (reused across all k-chunks)
  bf8 qf[2];
  const int q0 = w * 32;
#pragma unroll
  for (int mf = 0; mf < 2; ++mf)
    qf[mf] = *(const bf8*)(qkv + (size_t)(s * 256 + q0 + mf * 16 + l15) * 768 +
                           h * 32 + l4 * 8);

  __syncthreads();  // Vt ready (only cross-wave dependency)

  f32x4 o1[2][2], o2[2][2];
  float lsum[8];
#pragma unroll
  for (int mf = 0; mf < 2; ++mf)
#pragma unroll
    for (int nf = 0; nf < 2; ++nf) {
      o1[mf][nf] = (f32x4)(0.0f);
      o2[mf][nf] = (f32x4)(0.0f);
    }
#pragma unroll
  for (int i = 0; i < 8; ++i) lsum[i] = 0.0f;

  for (int kb = 0; kb < 4; ++kb) {
    // ---- S chunk = Q' · K^T (32q x 64k per wave), K frags from global
    f32x4 sa[2][4];
    __builtin_amdgcn_s_setprio(1);
#pragma unroll
    for (int nf = 0; nf < 4; ++nf) {
      bf8 kf = *(const bf8*)(qkv +
                             (size_t)(s * 256 + kb * 64 + nf * 16 + l15) * 768 +
                             256 + h * 32 + l4 * 8);
#pragma unroll
      for (int mf = 0; mf < 2; ++mf)
        sa[mf][nf] =
            __builtin_amdgcn_mfma_f32_16x16x32_bf16(qf[mf], kf, (f32x4)(0.0f), 0, 0, 0);
    }
    __builtin_amdgcn_s_setprio(0);

    // ---- exp2 + row-sum partials + spill P (bf16) to wave-private LDS
#pragma unroll
    for (int mf = 0; mf < 2; ++mf)
#pragma unroll
      for (int nf = 0; nf < 4; ++nf)
#pragma unroll
        for (int r = 0; r < 4; ++r) {
          float e = exp2f(sa[mf][nf][r]);
          lsum[mf * 4 + r] += e;
          Plds[w][mf * 16 + l4 * 4 + r][nf * 16 + l15] = f2bf(e);
        }
    // no barrier: Plds[w] is wave-private; lgkmcnt orders write->read

    // ---- PV (o1) and B·V (o2); bias frags direct from global
    __builtin_amdgcn_s_setprio(1);
#pragma unroll
    for (int ks = 0; ks < 2; ++ks) {
      bf8 vf[2];
#pragma unroll
      for (int nf = 0; nf < 2; ++nf)
        vf[nf] = *(const bf8*)(&Vt[nf * 16 + l15][kb * 64 + ks * 32 + l4 * 8]);
#pragma unroll
      for (int mf = 0; mf < 2; ++mf) {
        bf8 pf = *(const bf8*)(&Plds[w][mf * 16 + l15][ks * 32 + l4 * 8]);
        bf8 bfr = *(const bf8*)(bias + ((size_t)h * 256 + q0 + mf * 16 + l15) * 256 +
                                kb * 64 + ks * 32 + l4 * 8);
#pragma unroll
        for (int nf = 0; nf < 2; ++nf) {
          o1[mf][nf] = __builtin_amdgcn_mfma_f32_16x16x32_bf16(pf, vf[nf], o1[mf][nf], 0, 0, 0);
          o2[mf][nf] = __builtin_amdgcn_mfma_f32_16x16x32_bf16(bfr, vf[nf], o2[mf][nf], 0, 0, 0);
        }
      }
    }
    __builtin_amdgcn_s_setprio(0);
  }

  // ---- row sums: reduce over the 16 lanes sharing each q-row set
#pragma unroll
  for (int i = 0; i < 8; ++i) {
    float v = lsum[i];
    v += __shfl_xor(v, 1);
    v += __shfl_xor(v, 2);
    v += __shfl_xor(v, 4);
    v += __shfl_xor(v, 8);
    lsum[i] = 1.0f / v;
  }

  // ---- epilogue: normalize, add bias term, gate, store bf16
#pragma unroll
  for (int mf = 0; mf < 2; ++mf)
#pragma unroll
    for (int nf = 0; nf < 2; ++nf)
#pragma unroll
      for (int r = 0; r < 4; ++r) {
        const int q = q0 + mf * 16 + l4 * 4 + r;
        const int c = nf * 16 + l15;
        const size_t off = (size_t)(s * 256 + q) * 256 + h * 32 + c;
        float val = o1[mf][nf][r] * lsum[mf * 4 + r] + o2[mf][nf][r];
        attendg[off] = f2bf(val * bf2f(gate[off]));
      }
}

// ---------------------------------------------------------------------------
extern "C" void kernel_launch(void* const* d_in, const int* in_sizes, int n_in,
                              void* d_out, int out_size, void* d_ws,
                              size_t ws_size, hipStream_t stream) {
  const float* msa    = (const float*)d_in[0];  // [32768][256]
  const float* pair   = (const float*)d_in[1];  // [65536][128]
  const float* gate_w = (const float*)d_in[2];  // [256][256]
  const float* qkv_w  = (const float*)d_in[3];  // [256][768]
  const float* out_w  = (const float*)d_in[4];  // [256][256]
  const float* bias_w = (const float*)d_in[5];  // [128][8]
  float* out = (float*)d_out;                   // [32768][256] f32

  char* ws = (char*)d_ws;
  short* qkv_bf  = (short*)(ws);                 // 50,331,648 B
  short* msa_bf  = (short*)(ws + 50331648);      // 16,777,216 B
  short* gate_bf = (short*)(ws + 67108864);      // 16,777,216 B
  short* attendg = (short*)(ws + 83886080);      // 16,777,216 B
  short* bias_bf = (short*)(ws + 100663296);     //  1,048,576 B
  short* wcat_t  = (short*)(ws + 101711872);     //    524,288 B
  short* owt     = (short*)(ws + 102236160);     //    131,072 B

  const int M = 32768;

  convert_msa<<<2048, 256, 0, stream>>>(msa, msa_bf, M * 256 / 4);
  prep_all<<<1536, 256, 0, stream>>>(pair, bias_w, bias_bf, gate_w, qkv_w,
                                     out_w, wcat_t, owt);

  // gate|qkv fused GEMM: [M,256] @ [256,1024]  (grid transposed: x=m, y=n)
  gemm_bf16<0><<<dim3(M / 128, 8), 256, 0, stream>>>(
      msa_bf, wcat_t, gate_bf, qkv_bf, M, 1024, 256);

  attn_mfma<<<1024, 512, 0, stream>>>(qkv_bf, bias_bf, gate_bf, attendg);

  // out GEMM: [M,256] @ [256,256] -> f32  (grid transposed)
  gemm_bf16<1><<<dim3(M / 128, 2), 256, 0, stream>>>(
      attendg, owt, out, nullptr, M, 256, 256);
}